// Round 4
// baseline (1171.078 us; speedup 1.0000x reference)
//
#include <hip/hip_runtime.h>
#include <math.h>

#define N_NODES 50000
#define N_EDGES 800000
#define N_GRAPH 2000
#define F_INPUT 34
#define HID 256
#define NLAYER 5

typedef __attribute__((ext_vector_type(8))) short short8;
typedef __attribute__((ext_vector_type(4))) float float4v;

// ---------- helpers ----------
__device__ __forceinline__ float gelu_f(float x) {
  return 0.5f * x * (1.0f + erff(x * 0.70710678118654752440f));
}
__device__ __forceinline__ unsigned short bfr(float f) {  // fp32 -> bf16 RNE
  unsigned u = __float_as_uint(f);
  return (unsigned short)((u + 0x7fffu + ((u >> 16) & 1u)) >> 16);
}
__device__ __forceinline__ float b2f(unsigned short s) {
  return __uint_as_float(((unsigned)s) << 16);
}
__device__ __forceinline__ float b2f_lo(unsigned u) {  // low 16 bits = bf16
  return __uint_as_float(u << 16);
}
__device__ __forceinline__ float b2f_hi(unsigned u) {  // high 16 bits = bf16
  return __uint_as_float(u & 0xffff0000u);
}
__device__ __forceinline__ float4 ld4bf(const unsigned short* p) {
  ushort4 u = *(const ushort4*)p;
  float4 f;
  f.x = b2f(u.x); f.y = b2f(u.y); f.z = b2f(u.z); f.w = b2f(u.w);
  return f;
}
// async global->LDS, 16B per lane; lds dest = wave-uniform base + lane*16
__device__ __forceinline__ void acp16(const unsigned short* g, unsigned short* l) {
  __builtin_amdgcn_global_load_lds(
      (const __attribute__((address_space(1))) void*)g,
      (__attribute__((address_space(3))) void*)l, 16, 0, 0);
}

// ---------- fused input embed: h = gelu(LN(x @ in_W + b)), hb = bf16(h) ----------
// 16 rows/block, 256 threads. Thread (rr=t>>4, cg=t&15) computes 16 cols of row rr.
__global__ __launch_bounds__(256) void embed_fused(
    const float* __restrict__ x, const float* __restrict__ W,
    const float* __restrict__ bias, const float* __restrict__ gam,
    const float* __restrict__ bet, float* __restrict__ h,
    unsigned short* __restrict__ hb) {
  __shared__ float xs[16][34];   // 544 contiguous floats
  __shared__ float ys[16][256];
  int tid = threadIdx.x;
  int r0 = blockIdx.x * 16;      // N_NODES = 3125*16 exact
  float* xsf = &xs[0][0];
  for (int i = tid; i < 544; i += 256) xsf[i] = x[(size_t)r0 * 34 + i];
  __syncthreads();
  {
    int rr = tid >> 4;
    int c0 = (tid & 15) * 16;
    float acc[16];
#pragma unroll
    for (int j = 0; j < 16; j += 4) {
      float4 b4 = *(const float4*)&bias[c0 + j];
      acc[j] = b4.x; acc[j + 1] = b4.y; acc[j + 2] = b4.z; acc[j + 3] = b4.w;
    }
    for (int k = 0; k < 34; ++k) {
      float xv = xs[rr][k];
#pragma unroll
      for (int j = 0; j < 16; j += 4) {
        float4 w4 = *(const float4*)&W[(size_t)k * 256 + c0 + j];
        acc[j]     = fmaf(xv, w4.x, acc[j]);
        acc[j + 1] = fmaf(xv, w4.y, acc[j + 1]);
        acc[j + 2] = fmaf(xv, w4.z, acc[j + 2]);
        acc[j + 3] = fmaf(xv, w4.w, acc[j + 3]);
      }
    }
#pragma unroll
    for (int j = 0; j < 16; j += 4) {
      float4 o = {acc[j], acc[j + 1], acc[j + 2], acc[j + 3]};
      *(float4*)&ys[rr][c0 + j] = o;
    }
  }
  __syncthreads();
  int wv = tid >> 6, lane = tid & 63;
  for (int rr = wv * 4; rr < wv * 4 + 4; ++rr) {
    float4 v = *(const float4*)&ys[rr][lane * 4];
    float s = v.x + v.y + v.z + v.w;
    for (int o = 1; o < 64; o <<= 1) s += __shfl_xor(s, o);
    float mean = s * (1.f / 256.f);
    float d0 = v.x - mean, d1 = v.y - mean, d2 = v.z - mean, d3 = v.w - mean;
    float vs = d0 * d0 + d1 * d1 + d2 * d2 + d3 * d3;
    for (int o = 1; o < 64; o <<= 1) vs += __shfl_xor(vs, o);
    float inv = rsqrtf(vs * (1.f / 256.f) + 1e-5f);
    float4 g4 = *(const float4*)&gam[lane * 4];
    float4 b4 = *(const float4*)&bet[lane * 4];
    float y0 = gelu_f(d0 * inv * g4.x + b4.x);
    float y1 = gelu_f(d1 * inv * g4.y + b4.y);
    float y2 = gelu_f(d2 * inv * g4.z + b4.z);
    float y3 = gelu_f(d3 * inv * g4.w + b4.w);
    size_t idx = (size_t)(r0 + rr) * HID + lane * 4;
    float4 o4 = {y0, y1, y2, y3};
    *(float4*)&h[idx] = o4;
    ushort4 ob = {bfr(y0), bfr(y1), bfr(y2), bfr(y3)};
    *(ushort4*)&hb[idx] = ob;
  }
}

// ---------- bf16 MFMA GEMM (async LDS staging, BK=64) ----------
// A: [M][K] bf16 ; Bt: [Nn][K] bf16 ; bias fp32. K multiple of 64.
// flags: bit1 = write bf16 (LDS-coalesced epilogue), else fp32.
__global__ __launch_bounds__(256) void gemm_mfma(
    const unsigned short* __restrict__ A, const unsigned short* __restrict__ Bt,
    const float* __restrict__ bias, void* __restrict__ Cv,
    int M, int Nn, int K, int flags) {
  __shared__ unsigned short smem[16384];  // As[128][64]@0, Bs@8192; epilogue overlay
  unsigned short* As = smem;
  unsigned short* Bs = smem + 8192;
  int tid = threadIdx.x;
  int wave = tid >> 6, lane = tid & 63;

  // bijective XCD swizzle (m204 partition formula)
  int gx = gridDim.x;
  int flat = blockIdx.y * gx + blockIdx.x;
  int nwg = gx * gridDim.y;
  int xcd = flat & 7, idx = flat >> 3;
  int qb = nwg >> 3, r = nwg & 7;
  int g0 = xcd * qb + min(xcd, r);
  int wk = g0 + idx;
  int row0 = (wk / gx) * 128;
  int col0 = (wk % gx) * 128;

  int wm0 = (wave >> 1) * 64;
  int wn0 = (wave & 1) * 64;
  int q = lane >> 4;
  int ln = lane & 15;

  // staging: 8 issues x (64 lanes x 16B = 1KB/wave); issue i covers rows [i*32+wave*8, +8)
  int srow = wave * 8 + (lane >> 3);
  int scol = (lane & 7) * 8;
  const unsigned short* pa[4];
  const unsigned short* pb[4];
  unsigned short* la[4];
  unsigned short* lb[4];
#pragma unroll
  for (int i = 0; i < 4; ++i) {
    int ra = min(row0 + srow + i * 32, M - 1);
    pa[i] = A + (size_t)ra * K + scol;
    pb[i] = Bt + (size_t)(col0 + srow + i * 32) * K + scol;
    la[i] = As + (i * 32 + wave * 8) * 64;
    lb[i] = Bs + (i * 32 + wave * 8) * 64;
  }

  float4v acc[4][4];
#pragma unroll
  for (int i = 0; i < 4; ++i)
#pragma unroll
    for (int j = 0; j < 4; ++j) acc[i][j] = (float4v)0.f;

  for (int k0 = 0; k0 < K; k0 += 64) {
#pragma unroll
    for (int i = 0; i < 4; ++i) acp16(pa[i] + k0, la[i]);
#pragma unroll
    for (int i = 0; i < 4; ++i) acp16(pb[i] + k0, lb[i]);
    __syncthreads();
#pragma unroll
    for (int ks = 0; ks < 2; ++ks) {
      short8 af[4], bf[4];
#pragma unroll
      for (int i = 0; i < 4; ++i)
        af[i] = *(const short8*)&As[(wm0 + i * 16 + ln) * 64 + ks * 32 + q * 8];
#pragma unroll
      for (int j = 0; j < 4; ++j)
        bf[j] = *(const short8*)&Bs[(wn0 + j * 16 + ln) * 64 + ks * 32 + q * 8];
#pragma unroll
      for (int i = 0; i < 4; ++i)
#pragma unroll
        for (int j = 0; j < 4; ++j)
          acc[i][j] = __builtin_amdgcn_mfma_f32_16x16x32_bf16(af[i], bf[j], acc[i][j], 0, 0, 0);
    }
    __syncthreads();
  }
  int rb = (lane >> 4) * 4;
  if (flags & 2) {
    // LDS-transposed coalesced bf16 epilogue: per-wave 64x64 tile in 2 passes
    unsigned short* Cb = (unsigned short*)Cv;
    unsigned short* eb = smem + wave * 2560;  // 64 rows x stride 40
#pragma unroll
    for (int p = 0; p < 2; ++p) {
#pragma unroll
      for (int jj = 0; jj < 2; ++jj) {
        int j = p * 2 + jj;
        float bv = bias[col0 + wn0 + j * 16 + ln];
#pragma unroll
        for (int i = 0; i < 4; ++i)
#pragma unroll
          for (int r2 = 0; r2 < 4; ++r2)
            eb[(i * 16 + rb + r2) * 40 + jj * 16 + ln] = bfr(acc[i][j][r2] + bv);
      }
      int grow = row0 + wm0 + lane;
      uint4 w0 = *(uint4*)&eb[lane * 40 + 0];
      uint4 w1 = *(uint4*)&eb[lane * 40 + 8];
      uint4 w2 = *(uint4*)&eb[lane * 40 + 16];
      uint4 w3 = *(uint4*)&eb[lane * 40 + 24];
      if (grow < M) {
        unsigned short* dst = Cb + (size_t)grow * Nn + col0 + wn0 + p * 32;
        *(uint4*)&dst[0] = w0;
        *(uint4*)&dst[8] = w1;
        *(uint4*)&dst[16] = w2;
        *(uint4*)&dst[24] = w3;
      }
    }
  } else {
    float* C = (float*)Cv;
#pragma unroll
    for (int j = 0; j < 4; ++j) {
      int col = col0 + wn0 + j * 16 + ln;
      float bv = bias[col];
#pragma unroll
      for (int i = 0; i < 4; ++i)
#pragma unroll
        for (int r2 = 0; r2 < 4; ++r2) {
          int row = row0 + wm0 + i * 16 + rb + r2;
          if (row < M) C[(size_t)row * Nn + col] = acc[i][j][r2] + bv;
        }
    }
  }
}

// ---------- merged weight/bias prep (one dispatch) ----------
// z<14: Wt_bf16[n][k]=bf16(W[k][n]) slots 2l=Wl, 2l+1=Wr, 10=q, 11/12=kv-interleaved,
//       13=skip (kv: k-col c -> (c>>2)*8+(c&3), v-col c -> (c>>2)*8+4+(c&3))
// z==14: out_W [512][512] transpose -> bf16
// z==15: bias concat: [5][512]=bl|br ; [1024]=bq|kv-interleaved|bsk
__global__ __launch_bounds__(256) void prep_all(
    const float* __restrict__ Wl, const float* __restrict__ Wr,
    const float* __restrict__ Wq, const float* __restrict__ Wk,
    const float* __restrict__ Wv, const float* __restrict__ Wsk,
    unsigned short* __restrict__ outw,
    const float* __restrict__ Wout, unsigned short* __restrict__ outwout,
    const float* __restrict__ bl, const float* __restrict__ br,
    const float* __restrict__ bq, const float* __restrict__ bk,
    const float* __restrict__ bv, const float* __restrict__ bsk,
    float* __restrict__ bcat) {
  __shared__ float t[32][33];
  int z = blockIdx.z;
  int rr0 = threadIdx.x >> 5, c = threadIdx.x & 31;
  if (z < 14) {
    if (blockIdx.x >= 8 || blockIdx.y >= 8) return;
    const float* W = (z < 10) ? (((z & 1) ? Wr : Wl) + (size_t)(z >> 1) * 65536)
                   : (z == 10) ? Wq : (z == 11) ? Wk : (z == 12) ? Wv : Wsk;
    int k0 = blockIdx.y * 32, n0 = blockIdx.x * 32;
    for (int rr = rr0; rr < 32; rr += 8)
      t[rr][c] = W[(size_t)(k0 + rr) * HID + n0 + c];
    __syncthreads();
    for (int rr = rr0; rr < 32; rr += 8) {
      int n = n0 + rr;
      size_t row;
      if (z == 11)      row = 11 * 256 + (size_t)((n >> 2) * 8 + (n & 3));      // k
      else if (z == 12) row = 11 * 256 + (size_t)((n >> 2) * 8 + 4 + (n & 3));  // v
      else              row = (size_t)z * 256 + n;
      outw[row * HID + k0 + c] = bfr(t[c][rr]);
    }
  } else if (z == 14) {
    int k0 = blockIdx.y * 32, n0 = blockIdx.x * 32;
    for (int rr = rr0; rr < 32; rr += 8)
      t[rr][c] = Wout[(size_t)(k0 + rr) * 512 + n0 + c];
    __syncthreads();
    for (int rr = rr0; rr < 32; rr += 8)
      outwout[(size_t)(n0 + rr) * 512 + k0 + c] = bfr(t[c][rr]);
  } else {
    if (blockIdx.y != 0 || blockIdx.x >= 14) return;
    int i = blockIdx.x * 256 + threadIdx.x;
    if (i < 2560) {
      int l = i >> 9, cc = i & 511;
      bcat[i] = (cc < 256) ? bl[l * 256 + cc] : br[l * 256 + (cc - 256)];
    } else if (i < 3584) {
      int j = i - 2560;
      float v;
      if (j < 256) {
        v = bq[j];
      } else if (j < 768) {
        int p = j - 256;
        int hi = p >> 3, lo = p & 7;
        v = (lo < 4) ? bk[hi * 4 + lo] : bv[hi * 4 + (lo - 4)];
      } else {
        v = bsk[j - 768];
      }
      bcat[i] = v;
    }
  }
}

// ---------- LayerNorm standalone (final out) ----------
__global__ __launch_bounds__(256) void ln_act(
    const float* __restrict__ in, const float* __restrict__ gam,
    const float* __restrict__ bet, float* __restrict__ out,
    unsigned short* __restrict__ outb,
    int n_rows, int width, int do_gelu) {
  int wid = blockIdx.x * 4 + (threadIdx.x >> 6);
  int lane = threadIdx.x & 63;
  if (wid >= n_rows) return;
  int chunks = width >> 8;
  float4 v[2];
  float s = 0.f;
  for (int c = 0; c < chunks; ++c) {
    int off = c * 256 + lane * 4;
    float4 t = *(const float4*)&in[(size_t)wid * width + off];
    v[c] = t;
    s += t.x + t.y + t.z + t.w;
  }
  for (int o = 1; o < 64; o <<= 1) s += __shfl_xor(s, o);
  float mean = s / (float)width;
  float vs = 0.f;
  for (int c = 0; c < chunks; ++c) {
    float dx = v[c].x - mean, dy = v[c].y - mean, dz = v[c].z - mean, dw = v[c].w - mean;
    vs += dx * dx + dy * dy + dz * dz + dw * dw;
  }
  for (int o = 1; o < 64; o <<= 1) vs += __shfl_xor(vs, o);
  float inv = rsqrtf(vs / (float)width + 1e-5f);
  for (int c = 0; c < chunks; ++c) {
    int off = c * 256 + lane * 4;
    float4 g4 = *(const float4*)&gam[off];
    float4 b4 = *(const float4*)&bet[off];
    float y[4] = {(v[c].x - mean) * inv * g4.x + b4.x,
                  (v[c].y - mean) * inv * g4.y + b4.y,
                  (v[c].z - mean) * inv * g4.z + b4.z,
                  (v[c].w - mean) * inv * g4.w + b4.w};
    if (do_gelu) {
#pragma unroll
      for (int i = 0; i < 4; ++i) y[i] = gelu_f(y[i]);
    }
    size_t idx = (size_t)wid * width + off;
    float4 o4 = {y[0], y[1], y[2], y[3]};
    *(float4*)&out[idx] = o4;
    if (outb) {
      ushort4 ob = {bfr(y[0]), bfr(y[1]), bfr(y[2]), bfr(y[3])};
      *(ushort4*)&outb[idx] = ob;
    }
  }
}

// ---------- CSR build (two-level scan; block prefix folded into scan3) ----------
__global__ __launch_bounds__(256) void edge_count(const int* __restrict__ ei,
                                                  int* __restrict__ counts) {
  int e = blockIdx.x * 256 + threadIdx.x;
  if (e < N_EDGES) atomicAdd(&counts[ei[N_EDGES + e]], 1);
}

__global__ __launch_bounds__(1024) void scan1(const int* __restrict__ counts,
                                              int* __restrict__ indptr,
                                              int* __restrict__ bsums, int n) {
  __shared__ int sm[1024];
  int tid = threadIdx.x;
  int i = blockIdx.x * 1024 + tid;
  int v = (i < n) ? counts[i] : 0;
  sm[tid] = v;
  __syncthreads();
  for (int off = 1; off < 1024; off <<= 1) {
    int t = (tid >= off) ? sm[tid - off] : 0;
    __syncthreads();
    sm[tid] += t;
    __syncthreads();
  }
  if (i < n) indptr[i] = sm[tid] - v;  // block-local exclusive
  if (tid == 1023) bsums[blockIdx.x] = sm[1023];
}

__global__ __launch_bounds__(256) void scan3(const int* __restrict__ bsums,
                                             int* __restrict__ indptr,
                                             int* __restrict__ cursor, int n) {
  __shared__ int pre;
  int i = blockIdx.x * 256 + threadIdx.x;
  if (threadIdx.x == 0) {
    int nb = blockIdx.x >> 2;  // i>>10 constant within a 256-block
    int a = 0;
    for (int j = 0; j < nb; ++j) a += bsums[j];
    pre = a;
  }
  __syncthreads();
  if (i < n) {
    int v = indptr[i] + pre;
    indptr[i] = v;
    cursor[i] = v;
  }
  if (i == 0) indptr[n] = N_EDGES;
}

__global__ __launch_bounds__(256) void edge_scatter(const int* __restrict__ ei,
                                                    int* __restrict__ cursor,
                                                    int* __restrict__ esrc) {
  int e = blockIdx.x * 256 + threadIdx.x;
  if (e < N_EDGES) {
    int d = ei[N_EDGES + e];
    int p = atomicAdd(&cursor[d], 1);
    esrc[p] = ei[e];
  }
}

// ---------- GATv2 agg + bias + LN + GELU + residual (fused, branchless) ----------
// xlr[N][512] bf16 rows = [xl|xr]; writes h (fp32) and hb (bf16).
// Softmax anchored on self-loop score (shift-invariant; scores O(1), clamp +60).
#define GAT_EDGE(f)                                                        \
  {                                                                        \
    float ex = f.x + xri.x; ex = fmaxf(ex, 0.2f * ex);                     \
    float ey = f.y + xri.y; ey = fmaxf(ey, 0.2f * ey);                     \
    float ez = f.z + xri.z; ez = fmaxf(ez, 0.2f * ez);                     \
    float ew = f.w + xri.w; ew = fmaxf(ew, 0.2f * ew);                     \
    float p = ex * a4.x + ey * a4.y + ez * a4.z + ew * a4.w;               \
    p += __shfl_xor(p, 1); p += __shfl_xor(p, 2); p += __shfl_xor(p, 4);   \
    float wgt = __expf(fminf(p - m0, 60.f));                               \
    ax = fmaf(wgt, f.x, ax); ay = fmaf(wgt, f.y, ay);                      \
    az = fmaf(wgt, f.z, az); aw = fmaf(wgt, f.w, aw);                      \
    lsum += wgt;                                                           \
  }

__global__ __launch_bounds__(256) void gat_agg(
    const unsigned short* __restrict__ xlr, const float* __restrict__ att,
    const int* __restrict__ indptr, const int* __restrict__ esrc,
    const float* __restrict__ pre_bias, const float* __restrict__ gam,
    const float* __restrict__ bet, float* __restrict__ h,
    unsigned short* __restrict__ hb) {
  int wid = blockIdx.x * 4 + (threadIdx.x >> 6);
  int lane = threadIdx.x & 63;
  if (wid >= N_NODES) return;
  float4 xri = ld4bf(&xlr[(size_t)wid * 512 + 256 + lane * 4]);
  float4 a4 = *(const float4*)&att[lane * 4];
  int beg = indptr[wid], end = indptr[wid + 1];

  float m0, lsum, ax, ay, az, aw;
  {  // self loop = softmax anchor
    float4 f = ld4bf(&xlr[(size_t)wid * 512 + lane * 4]);
    float ex = f.x + xri.x; ex = fmaxf(ex, 0.2f * ex);
    float ey = f.y + xri.y; ey = fmaxf(ey, 0.2f * ey);
    float ez = f.z + xri.z; ez = fmaxf(ez, 0.2f * ez);
    float ew = f.w + xri.w; ew = fmaxf(ew, 0.2f * ew);
    float p = ex * a4.x + ey * a4.y + ez * a4.z + ew * a4.w;
    p += __shfl_xor(p, 1); p += __shfl_xor(p, 2); p += __shfl_xor(p, 4);
    m0 = p; lsum = 1.f;
    ax = f.x; ay = f.y; az = f.z; aw = f.w;
  }
  const unsigned short* xbase = xlr + lane * 4;
  int e = beg;
  for (; e + 3 < end; e += 4) {  // 4 gathers in flight
    int j0 = esrc[e], j1 = esrc[e + 1], j2 = esrc[e + 2], j3 = esrc[e + 3];
    float4 f0 = ld4bf(xbase + (size_t)j0 * 512);
    float4 f1 = ld4bf(xbase + (size_t)j1 * 512);
    float4 f2 = ld4bf(xbase + (size_t)j2 * 512);
    float4 f3 = ld4bf(xbase + (size_t)j3 * 512);
    GAT_EDGE(f0); GAT_EDGE(f1); GAT_EDGE(f2); GAT_EDGE(f3);
  }
  for (; e < end; ++e) {
    int j = esrc[e];
    float4 f = ld4bf(xbase + (size_t)j * 512);
    GAT_EDGE(f);
  }
  float inv = 1.f / (lsum + 1e-16f);
  float4 pb = *(const float4*)&pre_bias[lane * 4];
  float y0 = ax * inv + pb.x, y1 = ay * inv + pb.y;
  float y2 = az * inv + pb.z, y3 = aw * inv + pb.w;
  // LN over 256
  float s = y0 + y1 + y2 + y3;
  for (int o = 1; o < 64; o <<= 1) s += __shfl_xor(s, o);
  float mean = s * (1.f / 256.f);
  float d0 = y0 - mean, d1 = y1 - mean, d2 = y2 - mean, d3 = y3 - mean;
  float vs = d0 * d0 + d1 * d1 + d2 * d2 + d3 * d3;
  for (int o = 1; o < 64; o <<= 1) vs += __shfl_xor(vs, o);
  float inv2 = rsqrtf(vs * (1.f / 256.f) + 1e-5f);
  float4 g4 = *(const float4*)&gam[lane * 4];
  float4 b4 = *(const float4*)&bet[lane * 4];
  y0 = gelu_f(d0 * inv2 * g4.x + b4.x);
  y1 = gelu_f(d1 * inv2 * g4.y + b4.y);
  y2 = gelu_f(d2 * inv2 * g4.z + b4.z);
  y3 = gelu_f(d3 * inv2 * g4.w + b4.w);
  size_t idx = (size_t)wid * HID + lane * 4;
  float4 r4 = *(const float4*)&h[idx];
  y0 += r4.x; y1 += r4.y; y2 += r4.z; y3 += r4.w;
  float4 o4 = {y0, y1, y2, y3};
  *(float4*)&h[idx] = o4;
  ushort4 ob = {bfr(y0), bfr(y1), bfr(y2), bfr(y3)};
  *(ushort4*)&hb[idx] = ob;
}

// ---------- TransformerConv agg + skip + LN + residual (fused, branchless) ----------
// qkv[N][1024] bf16 rows = [q | kv-interleaved | skip]; per edge ONE dwordx4
// gives lane's k[4] (u_.x,u_.y) and v[4] (u_.z,u_.w). scale pre-folded into qi.
#define TR_EDGE(u_)                                                         \
  {                                                                         \
    float p = qi.x * b2f_lo(u_.x);                                          \
    p = fmaf(qi.y, b2f_hi(u_.x), p);                                        \
    p = fmaf(qi.z, b2f_lo(u_.y), p);                                        \
    p = fmaf(qi.w, b2f_hi(u_.y), p);                                        \
    p += __shfl_xor(p, 1); p += __shfl_xor(p, 2); p += __shfl_xor(p, 4);    \
    float wgt = __expf(fminf(p, 60.f));                                     \
    ax = fmaf(wgt, b2f_lo(u_.z), ax); ay = fmaf(wgt, b2f_hi(u_.z), ay);     \
    az = fmaf(wgt, b2f_lo(u_.w), az); aw = fmaf(wgt, b2f_hi(u_.w), aw);     \
    lsum += wgt;                                                            \
  }

__global__ __launch_bounds__(256) void tr_agg(
    const unsigned short* __restrict__ qkv, const int* __restrict__ indptr,
    const int* __restrict__ esrc,
    const float* __restrict__ gam, const float* __restrict__ bet,
    float* __restrict__ h) {
  int wid = blockIdx.x * 4 + (threadIdx.x >> 6);
  int lane = threadIdx.x & 63;
  if (wid >= N_NODES) return;
  const float scale = 0.17677669529663687f;
  float4 qi = ld4bf(&qkv[(size_t)wid * 1024 + lane * 4]);
  qi.x *= scale; qi.y *= scale; qi.z *= scale; qi.w *= scale;
  const unsigned short* kvbase = qkv + 256 + lane * 8;
  int beg = indptr[wid], end = indptr[wid + 1];
  float lsum = 0.f;
  float ax = 0.f, ay = 0.f, az = 0.f, aw = 0.f;
  int e = beg;
  for (; e + 3 < end; e += 4) {  // 4 dwordx4 gathers in flight
    int j0 = esrc[e], j1 = esrc[e + 1], j2 = esrc[e + 2], j3 = esrc[e + 3];
    uint4 u0 = *(const uint4*)(kvbase + (size_t)j0 * 1024);
    uint4 u1 = *(const uint4*)(kvbase + (size_t)j1 * 1024);
    uint4 u2 = *(const uint4*)(kvbase + (size_t)j2 * 1024);
    uint4 u3 = *(const uint4*)(kvbase + (size_t)j3 * 1024);
    TR_EDGE(u0); TR_EDGE(u1); TR_EDGE(u2); TR_EDGE(u3);
  }
  for (; e < end; ++e) {
    uint4 u0 = *(const uint4*)(kvbase + (size_t)esrc[e] * 1024);
    TR_EDGE(u0);
  }
  float inv = 1.f / (lsum + 1e-16f);
  size_t idx = (size_t)wid * HID + lane * 4;
  float4 sk = ld4bf(&qkv[(size_t)wid * 1024 + 768 + lane * 4]);
  float y0 = ax * inv + sk.x, y1 = ay * inv + sk.y;
  float y2 = az * inv + sk.z, y3 = aw * inv + sk.w;
  // LN over 256 (no gelu)
  float s = y0 + y1 + y2 + y3;
  for (int o = 1; o < 64; o <<= 1) s += __shfl_xor(s, o);
  float mean = s * (1.f / 256.f);
  float d0 = y0 - mean, d1 = y1 - mean, d2 = y2 - mean, d3 = y3 - mean;
  float vs = d0 * d0 + d1 * d1 + d2 * d2 + d3 * d3;
  for (int o = 1; o < 64; o <<= 1) vs += __shfl_xor(vs, o);
  float inv2 = rsqrtf(vs * (1.f / 256.f) + 1e-5f);
  float4 g4 = *(const float4*)&gam[lane * 4];
  float4 b4 = *(const float4*)&bet[lane * 4];
  float4 r4 = *(const float4*)&h[idx];
  float4 o4;
  o4.x = r4.x + d0 * inv2 * g4.x + b4.x;
  o4.y = r4.y + d1 * inv2 * g4.y + b4.y;
  o4.z = r4.z + d2 * inv2 * g4.z + b4.z;
  o4.w = r4.w + d3 * inv2 * g4.w + b4.w;
  *(float4*)&h[idx] = o4;
}

// ---------- pooling over sorted batch ----------
__global__ __launch_bounds__(256) void graph_bounds(const int* __restrict__ batch,
                                                    int* __restrict__ gptr) {
  int i = blockIdx.x * 256 + threadIdx.x;
  if (i >= N_NODES) return;
  int b0 = batch[i];
  if (i == 0)
    for (int g = 0; g <= b0; ++g) gptr[g] = 0;
  int b1 = (i + 1 < N_NODES) ? batch[i + 1] : N_GRAPH;
  for (int g = b0 + 1; g <= b1; ++g) gptr[g] = i + 1;
}

__global__ __launch_bounds__(256) void pool_seg(
    const float* __restrict__ h, const int* __restrict__ gptr,
    unsigned short* __restrict__ geb) {
  int g = blockIdx.x, c = threadIdx.x;
  int s = gptr[g], e = gptr[g + 1];
  float sum = 0.f, mx = -INFINITY;
  for (int r = s; r < e; ++r) {
    float vv = h[(size_t)r * HID + c];
    sum += vv;
    mx = fmaxf(mx, vv);
  }
  int cnt = e - s;
  geb[(size_t)g * 512 + c] = bfr(sum / (float)max(cnt, 1));
  geb[(size_t)g * 512 + 256 + c] = bfr(cnt ? mx : 0.f);
}

// ---------- host ----------
static inline void mfma_launch(const unsigned short* A, const unsigned short* Bt,
                               const float* bias, void* C, int M, int Nn, int K,
                               int flags, hipStream_t s) {
  dim3 grid(Nn / 128, (M + 127) / 128);
  gemm_mfma<<<grid, 256, 0, s>>>(A, Bt, bias, C, M, Nn, K, flags);
}

extern "C" void kernel_launch(void* const* d_in, const int* in_sizes, int n_in,
                              void* d_out, int out_size, void* d_ws, size_t ws_size,
                              hipStream_t stream) {
  const float* x       = (const float*)d_in[0];
  const int*   ei      = (const int*)d_in[1];
  const int*   batch   = (const int*)d_in[2];
  const float* in_W    = (const float*)d_in[3];
  const float* in_b    = (const float*)d_in[4];
  const float* in_ln_g = (const float*)d_in[5];
  const float* in_ln_b = (const float*)d_in[6];
  const float* gat_Wl  = (const float*)d_in[7];
  const float* gat_bl  = (const float*)d_in[8];
  const float* gat_Wr  = (const float*)d_in[9];
  const float* gat_br  = (const float*)d_in[10];
  const float* gat_att = (const float*)d_in[11];
  const float* gat_bias= (const float*)d_in[12];
  const float* gat_ln_g= (const float*)d_in[13];
  const float* gat_ln_b= (const float*)d_in[14];
  const float* tr_Wq   = (const float*)d_in[15];
  const float* tr_bq   = (const float*)d_in[16];
  const float* tr_Wk   = (const float*)d_in[17];
  const float* tr_bk   = (const float*)d_in[18];
  const float* tr_Wv   = (const float*)d_in[19];
  const float* tr_bv   = (const float*)d_in[20];
  const float* tr_Wsk  = (const float*)d_in[21];
  const float* tr_bsk  = (const float*)d_in[22];
  const float* tr_ln_g = (const float*)d_in[23];
  const float* tr_ln_b = (const float*)d_in[24];
  const float* out_W   = (const float*)d_in[25];
  const float* out_b   = (const float*)d_in[26];
  const float* out_ln_g= (const float*)d_in[27];
  const float* out_ln_b= (const float*)d_in[28];

  // ---- workspace (256B-aligned) ----
  char* w = (char*)d_ws;
  auto take = [&](size_t bytes) -> char* {
    char* p = w;
    w += (bytes + 255) & ~(size_t)255;
    return p;
  };
  const size_t NB = (size_t)N_NODES * HID * sizeof(float);
  float* h    = (float*)take(NB);                                    // 51.2 MB
  unsigned short* hb  = (unsigned short*)take((size_t)N_NODES * HID * 2);   // 25.6 MB
  unsigned short* xq  = (unsigned short*)take((size_t)N_NODES * 1024 * 2);  // 102.4 MB
  unsigned short* wbuf= (unsigned short*)take((size_t)(14 * 65536 + 262144) * 2);
  float* bcat = (float*)take(3584 * sizeof(float));
  int* indptr = (int*)take((N_NODES + 1) * sizeof(int));
  int* cursor = (int*)take(N_NODES * sizeof(int));
  int* counts = (int*)take(N_NODES * sizeof(int));
  int* esrc   = (int*)take(N_EDGES * sizeof(int));
  int* bsums  = (int*)take(64 * sizeof(int));
  // pool/output scratch overlays xq (free after tr_agg)
  char* w2 = (char*)xq;
  auto take2 = [&](size_t bytes) -> char* {
    char* p = w2;
    w2 += (bytes + 255) & ~(size_t)255;
    return p;
  };
  int* gptr = (int*)take2((N_GRAPH + 1) * sizeof(int));
  unsigned short* geb = (unsigned short*)take2((size_t)N_GRAPH * 512 * 2);
  float* tbuf = (float*)take2((size_t)N_GRAPH * 512 * sizeof(float));

  const int EB = (N_EDGES + 255) / 256;
  const int WB = (N_NODES + 3) / 4;
  const int NSB = (N_NODES + 1023) / 1024;

  // --- merged weight/bias prep (1 dispatch) ---
  {
    dim3 g(16, 16, 16);
    prep_all<<<g, 256, 0, stream>>>(gat_Wl, gat_Wr, tr_Wq, tr_Wk, tr_Wv, tr_Wsk,
                                    wbuf, out_W, wbuf + (size_t)14 * 65536,
                                    gat_bl, gat_br, tr_bq, tr_bk, tr_bv, tr_bsk,
                                    bcat);
  }

  // --- CSR (dst-sorted), two-level scan (scan2 folded into scan3) ---
  hipMemsetAsync(counts, 0, N_NODES * sizeof(int), stream);
  edge_count<<<EB, 256, 0, stream>>>(ei, counts);
  scan1<<<NSB, 1024, 0, stream>>>(counts, indptr, bsums, N_NODES);
  scan3<<<(N_NODES + 255) / 256, 256, 0, stream>>>(bsums, indptr, cursor, N_NODES);
  edge_scatter<<<EB, 256, 0, stream>>>(ei, cursor, esrc);

  // --- fused input embed: h = gelu(LN(x @ in_W + in_b)), hb = bf16(h) ---
  embed_fused<<<N_NODES / 16, 256, 0, stream>>>(x, in_W, in_b, in_ln_g, in_ln_b,
                                                h, hb);

  // --- 5 GATv2 layers: fused Wl|Wr GEMM -> xq[N][512] bf16; fused agg+LN ---
  for (int l = 0; l < NLAYER; ++l) {
    mfma_launch(hb, wbuf + (size_t)(2 * l) * 65536, bcat + l * 512, xq,
                N_NODES, 512, HID, 2, stream);
    gat_agg<<<WB, 256, 0, stream>>>(xq, gat_att + l * HID, indptr, esrc,
                                    gat_bias + l * HID, gat_ln_g + l * HID,
                                    gat_ln_b + l * HID, h, hb);
  }

  // --- TransformerConv: merged q|kv|skip GEMM (Nn=1024), fused agg+LN ---
  mfma_launch(hb, wbuf + (size_t)10 * 65536, bcat + 2560, xq,
              N_NODES, 1024, HID, 2, stream);
  tr_agg<<<WB, 256, 0, stream>>>(xq, indptr, esrc, tr_ln_g, tr_ln_b, h);

  // --- pooling (sorted batch; scratch overlays xq, now free) -> geb bf16 ---
  graph_bounds<<<(N_NODES + 255) / 256, 256, 0, stream>>>(batch, gptr);
  pool_seg<<<N_GRAPH, 256, 0, stream>>>(h, gptr, geb);

  // --- output proj (MFMA): tbuf = geb @ out_W + out_b ; then LN+GELU ---
  mfma_launch(geb, wbuf + (size_t)14 * 65536, out_b, tbuf,
              N_GRAPH, 512, 512, 0, stream);
  ln_act<<<(N_GRAPH + 3) / 4, 256, 0, stream>>>(tbuf, out_ln_g, out_ln_b,
                                                (float*)d_out, nullptr,
                                                N_GRAPH, 512, 1);
}

// Round 5
// 1140.084 us; speedup vs baseline: 1.0272x; 1.0272x over previous
//
#include <hip/hip_runtime.h>
#include <math.h>

#define N_NODES 50000
#define N_EDGES 800000
#define N_GRAPH 2000
#define F_INPUT 34
#define HID 256
#define NLAYER 5

typedef __attribute__((ext_vector_type(8))) short short8;
typedef __attribute__((ext_vector_type(4))) float float4v;

// ---------- helpers ----------
__device__ __forceinline__ float gelu_f(float x) {
  return 0.5f * x * (1.0f + erff(x * 0.70710678118654752440f));
}
__device__ __forceinline__ unsigned short bfr(float f) {  // fp32 -> bf16 RNE
  unsigned u = __float_as_uint(f);
  return (unsigned short)((u + 0x7fffu + ((u >> 16) & 1u)) >> 16);
}
__device__ __forceinline__ float b2f(unsigned short s) {
  return __uint_as_float(((unsigned)s) << 16);
}
__device__ __forceinline__ float b2f_lo(unsigned u) {  // low 16 bits = bf16
  return __uint_as_float(u << 16);
}
__device__ __forceinline__ float b2f_hi(unsigned u) {  // high 16 bits = bf16
  return __uint_as_float(u & 0xffff0000u);
}
__device__ __forceinline__ float4 ld4bf(const unsigned short* p) {
  ushort4 u = *(const ushort4*)p;
  float4 f;
  f.x = b2f(u.x); f.y = b2f(u.y); f.z = b2f(u.z); f.w = b2f(u.w);
  return f;
}
// async global->LDS, 16B per lane; lds dest = wave-uniform base + lane*16
__device__ __forceinline__ void acp16(const unsigned short* g, unsigned short* l) {
  __builtin_amdgcn_global_load_lds(
      (const __attribute__((address_space(1))) void*)g,
      (__attribute__((address_space(3))) void*)l, 16, 0, 0);
}

// ---------- fused input embed: h = gelu(LN(x @ in_W + b)), hb = bf16(h) ----------
// 16 rows/block, 256 threads. Thread (rr=t>>4, cg=t&15) computes 16 cols of row rr.
__global__ __launch_bounds__(256) void embed_fused(
    const float* __restrict__ x, const float* __restrict__ W,
    const float* __restrict__ bias, const float* __restrict__ gam,
    const float* __restrict__ bet, float* __restrict__ h,
    unsigned short* __restrict__ hb) {
  __shared__ float xs[16][34];    // 544 contiguous floats
  __shared__ float ys[16][264];   // stride 264: 16B-aligned rows, +8-bank skew
  int tid = threadIdx.x;
  int r0 = blockIdx.x * 16;       // N_NODES = 3125*16 exact
  float* xsf = &xs[0][0];
  for (int i = tid; i < 544; i += 256) xsf[i] = x[(size_t)r0 * 34 + i];
  __syncthreads();
  {
    int rr = tid >> 4;
    int c0 = (tid & 15) * 16;
    float acc[16];
#pragma unroll
    for (int j = 0; j < 16; j += 4) {
      float4 b4 = *(const float4*)&bias[c0 + j];
      acc[j] = b4.x; acc[j + 1] = b4.y; acc[j + 2] = b4.z; acc[j + 3] = b4.w;
    }
    for (int k = 0; k < 34; ++k) {
      float xv = xs[rr][k];
#pragma unroll
      for (int j = 0; j < 16; j += 4) {
        float4 w4 = *(const float4*)&W[(size_t)k * 256 + c0 + j];
        acc[j]     = fmaf(xv, w4.x, acc[j]);
        acc[j + 1] = fmaf(xv, w4.y, acc[j + 1]);
        acc[j + 2] = fmaf(xv, w4.z, acc[j + 2]);
        acc[j + 3] = fmaf(xv, w4.w, acc[j + 3]);
      }
    }
#pragma unroll
    for (int j = 0; j < 16; j += 4) {
      float4 o = {acc[j], acc[j + 1], acc[j + 2], acc[j + 3]};
      *(float4*)&ys[rr][c0 + j] = o;
    }
  }
  __syncthreads();
  int wv = tid >> 6, lane = tid & 63;
  for (int rr = wv * 4; rr < wv * 4 + 4; ++rr) {
    float4 v = *(const float4*)&ys[rr][lane * 4];
    float s = v.x + v.y + v.z + v.w;
    for (int o = 1; o < 64; o <<= 1) s += __shfl_xor(s, o);
    float mean = s * (1.f / 256.f);
    float d0 = v.x - mean, d1 = v.y - mean, d2 = v.z - mean, d3 = v.w - mean;
    float vs = d0 * d0 + d1 * d1 + d2 * d2 + d3 * d3;
    for (int o = 1; o < 64; o <<= 1) vs += __shfl_xor(vs, o);
    float inv = rsqrtf(vs * (1.f / 256.f) + 1e-5f);
    float4 g4 = *(const float4*)&gam[lane * 4];
    float4 b4 = *(const float4*)&bet[lane * 4];
    float y0 = gelu_f(d0 * inv * g4.x + b4.x);
    float y1 = gelu_f(d1 * inv * g4.y + b4.y);
    float y2 = gelu_f(d2 * inv * g4.z + b4.z);
    float y3 = gelu_f(d3 * inv * g4.w + b4.w);
    size_t idx = (size_t)(r0 + rr) * HID + lane * 4;
    float4 o4 = {y0, y1, y2, y3};
    *(float4*)&h[idx] = o4;
    ushort4 ob = {bfr(y0), bfr(y1), bfr(y2), bfr(y3)};
    *(ushort4*)&hb[idx] = ob;
  }
}

// ---------- bf16 MFMA GEMM (async LDS staging, BK=64, XOR-swizzled LDS) ----------
// A: [M][K] bf16 ; Bt: [Nn][K] bf16 ; bias fp32. K multiple of 64.
// flags: bit1 = write bf16 (LDS-coalesced epilogue), else fp32.
// Swizzle (T2/rule#21): LDS rows are 64 shorts (128B) = 8 chunks of 16B.
// LDS[row][c] holds global [row][c ^ (row&7)]; staging keeps linear LDS dest
// and pre-swizzles the GLOBAL source chunk; reads XOR the chunk index.
// Result: ds_read_b128 spreads 8 chunk values over all 32 banks (2 lanes/bank).
__global__ __launch_bounds__(256) void gemm_mfma(
    const unsigned short* __restrict__ A, const unsigned short* __restrict__ Bt,
    const float* __restrict__ bias, void* __restrict__ Cv,
    int M, int Nn, int K, int flags) {
  __shared__ unsigned short smem[16384];  // As[128][64]@0, Bs@8192; epilogue overlay
  unsigned short* As = smem;
  unsigned short* Bs = smem + 8192;
  int tid = threadIdx.x;
  int wave = tid >> 6, lane = tid & 63;

  // bijective XCD swizzle (m204 partition formula)
  int gx = gridDim.x;
  int flat = blockIdx.y * gx + blockIdx.x;
  int nwg = gx * gridDim.y;
  int xcd = flat & 7, idx = flat >> 3;
  int qb = nwg >> 3, r = nwg & 7;
  int g0 = xcd * qb + min(xcd, r);
  int wk = g0 + idx;
  int row0 = (wk / gx) * 128;
  int col0 = (wk % gx) * 128;

  int wm0 = (wave >> 1) * 64;
  int wn0 = (wave & 1) * 64;
  int q = lane >> 4;
  int ln = lane & 15;

  // staging: 8 issues x (64 lanes x 16B = 1KB/wave); issue i covers rows [i*32+wave*8, +8)
  // lane's LDS slot: row = base + (lane>>3), chunk = lane&7 ; row&7 == lane>>3
  // -> global source chunk = (lane&7) ^ (lane>>3)  (inverse swizzle, involution)
  int srow = wave * 8 + (lane >> 3);
  int scol = ((lane & 7) ^ (lane >> 3)) * 8;
  const unsigned short* pa[4];
  const unsigned short* pb[4];
  unsigned short* la[4];
  unsigned short* lb[4];
#pragma unroll
  for (int i = 0; i < 4; ++i) {
    int ra = min(row0 + srow + i * 32, M - 1);
    pa[i] = A + (size_t)ra * K + scol;
    pb[i] = Bt + (size_t)(col0 + srow + i * 32) * K + scol;
    la[i] = As + (i * 32 + wave * 8) * 64;
    lb[i] = Bs + (i * 32 + wave * 8) * 64;
  }

  float4v acc[4][4];
#pragma unroll
  for (int i = 0; i < 4; ++i)
#pragma unroll
    for (int j = 0; j < 4; ++j) acc[i][j] = (float4v)0.f;

  for (int k0 = 0; k0 < K; k0 += 64) {
#pragma unroll
    for (int i = 0; i < 4; ++i) acp16(pa[i] + k0, la[i]);
#pragma unroll
    for (int i = 0; i < 4; ++i) acp16(pb[i] + k0, lb[i]);
    __syncthreads();
#pragma unroll
    for (int ks = 0; ks < 2; ++ks) {
      // fragment row = wm0|wn0 + i*16 + ln ; row&7 = ln&7
      // want global chunk (ks*4+q) -> read LDS chunk (ks*4+q)^(ln&7)
      int ch = ((ks * 4 + q) ^ (ln & 7)) * 8;
      short8 af[4], bf[4];
#pragma unroll
      for (int i = 0; i < 4; ++i)
        af[i] = *(const short8*)&As[(wm0 + i * 16 + ln) * 64 + ch];
#pragma unroll
      for (int j = 0; j < 4; ++j)
        bf[j] = *(const short8*)&Bs[(wn0 + j * 16 + ln) * 64 + ch];
#pragma unroll
      for (int i = 0; i < 4; ++i)
#pragma unroll
        for (int j = 0; j < 4; ++j)
          acc[i][j] = __builtin_amdgcn_mfma_f32_16x16x32_bf16(af[i], bf[j], acc[i][j], 0, 0, 0);
    }
    __syncthreads();
  }
  int rb = (lane >> 4) * 4;
  if (flags & 2) {
    // LDS-transposed coalesced bf16 epilogue: per-wave 64x64 tile in 2 passes
    unsigned short* Cb = (unsigned short*)Cv;
    unsigned short* eb = smem + wave * 2560;  // 64 rows x stride 40
#pragma unroll
    for (int p = 0; p < 2; ++p) {
#pragma unroll
      for (int jj = 0; jj < 2; ++jj) {
        int j = p * 2 + jj;
        float bv = bias[col0 + wn0 + j * 16 + ln];
#pragma unroll
        for (int i = 0; i < 4; ++i)
#pragma unroll
          for (int r2 = 0; r2 < 4; ++r2)
            eb[(i * 16 + rb + r2) * 40 + jj * 16 + ln] = bfr(acc[i][j][r2] + bv);
      }
      int grow = row0 + wm0 + lane;
      uint4 w0 = *(uint4*)&eb[lane * 40 + 0];
      uint4 w1 = *(uint4*)&eb[lane * 40 + 8];
      uint4 w2 = *(uint4*)&eb[lane * 40 + 16];
      uint4 w3 = *(uint4*)&eb[lane * 40 + 24];
      if (grow < M) {
        unsigned short* dst = Cb + (size_t)grow * Nn + col0 + wn0 + p * 32;
        *(uint4*)&dst[0] = w0;
        *(uint4*)&dst[8] = w1;
        *(uint4*)&dst[16] = w2;
        *(uint4*)&dst[24] = w3;
      }
    }
  } else {
    float* C = (float*)Cv;
#pragma unroll
    for (int j = 0; j < 4; ++j) {
      int col = col0 + wn0 + j * 16 + ln;
      float bv = bias[col];
#pragma unroll
      for (int i = 0; i < 4; ++i)
#pragma unroll
        for (int r2 = 0; r2 < 4; ++r2) {
          int row = row0 + wm0 + i * 16 + rb + r2;
          if (row < M) C[(size_t)row * Nn + col] = acc[i][j][r2] + bv;
        }
    }
  }
}

// ---------- merged weight/bias prep (one dispatch) ----------
// z<14: Wt_bf16[n][k]=bf16(W[k][n]) slots 2l=Wl, 2l+1=Wr, 10=q, 11/12=kv-interleaved,
//       13=skip (kv: k-col c -> (c>>2)*8+(c&3), v-col c -> (c>>2)*8+4+(c&3))
// z==14: out_W [512][512] transpose -> bf16
// z==15: bias concat: [5][512]=bl|br ; [1024]=bq|kv-interleaved|bsk
__global__ __launch_bounds__(256) void prep_all(
    const float* __restrict__ Wl, const float* __restrict__ Wr,
    const float* __restrict__ Wq, const float* __restrict__ Wk,
    const float* __restrict__ Wv, const float* __restrict__ Wsk,
    unsigned short* __restrict__ outw,
    const float* __restrict__ Wout, unsigned short* __restrict__ outwout,
    const float* __restrict__ bl, const float* __restrict__ br,
    const float* __restrict__ bq, const float* __restrict__ bk,
    const float* __restrict__ bv, const float* __restrict__ bsk,
    float* __restrict__ bcat) {
  __shared__ float t[32][33];
  int z = blockIdx.z;
  int rr0 = threadIdx.x >> 5, c = threadIdx.x & 31;
  if (z < 14) {
    if (blockIdx.x >= 8 || blockIdx.y >= 8) return;
    const float* W = (z < 10) ? (((z & 1) ? Wr : Wl) + (size_t)(z >> 1) * 65536)
                   : (z == 10) ? Wq : (z == 11) ? Wk : (z == 12) ? Wv : Wsk;
    int k0 = blockIdx.y * 32, n0 = blockIdx.x * 32;
    for (int rr = rr0; rr < 32; rr += 8)
      t[rr][c] = W[(size_t)(k0 + rr) * HID + n0 + c];
    __syncthreads();
    for (int rr = rr0; rr < 32; rr += 8) {
      int n = n0 + rr;
      size_t row;
      if (z == 11)      row = 11 * 256 + (size_t)((n >> 2) * 8 + (n & 3));      // k
      else if (z == 12) row = 11 * 256 + (size_t)((n >> 2) * 8 + 4 + (n & 3));  // v
      else              row = (size_t)z * 256 + n;
      outw[row * HID + k0 + c] = bfr(t[c][rr]);
    }
  } else if (z == 14) {
    int k0 = blockIdx.y * 32, n0 = blockIdx.x * 32;
    for (int rr = rr0; rr < 32; rr += 8)
      t[rr][c] = Wout[(size_t)(k0 + rr) * 512 + n0 + c];
    __syncthreads();
    for (int rr = rr0; rr < 32; rr += 8)
      outwout[(size_t)(n0 + rr) * 512 + k0 + c] = bfr(t[c][rr]);
  } else {
    if (blockIdx.y != 0 || blockIdx.x >= 14) return;
    int i = blockIdx.x * 256 + threadIdx.x;
    if (i < 2560) {
      int l = i >> 9, cc = i & 511;
      bcat[i] = (cc < 256) ? bl[l * 256 + cc] : br[l * 256 + (cc - 256)];
    } else if (i < 3584) {
      int j = i - 2560;
      float v;
      if (j < 256) {
        v = bq[j];
      } else if (j < 768) {
        int p = j - 256;
        int hi = p >> 3, lo = p & 7;
        v = (lo < 4) ? bk[hi * 4 + lo] : bv[hi * 4 + (lo - 4)];
      } else {
        v = bsk[j - 768];
      }
      bcat[i] = v;
    }
  }
}

// ---------- LayerNorm standalone (final out) ----------
__global__ __launch_bounds__(256) void ln_act(
    const float* __restrict__ in, const float* __restrict__ gam,
    const float* __restrict__ bet, float* __restrict__ out,
    unsigned short* __restrict__ outb,
    int n_rows, int width, int do_gelu) {
  int wid = blockIdx.x * 4 + (threadIdx.x >> 6);
  int lane = threadIdx.x & 63;
  if (wid >= n_rows) return;
  int chunks = width >> 8;
  float4 v[2];
  float s = 0.f;
  for (int c = 0; c < chunks; ++c) {
    int off = c * 256 + lane * 4;
    float4 t = *(const float4*)&in[(size_t)wid * width + off];
    v[c] = t;
    s += t.x + t.y + t.z + t.w;
  }
  for (int o = 1; o < 64; o <<= 1) s += __shfl_xor(s, o);
  float mean = s / (float)width;
  float vs = 0.f;
  for (int c = 0; c < chunks; ++c) {
    float dx = v[c].x - mean, dy = v[c].y - mean, dz = v[c].z - mean, dw = v[c].w - mean;
    vs += dx * dx + dy * dy + dz * dz + dw * dw;
  }
  for (int o = 1; o < 64; o <<= 1) vs += __shfl_xor(vs, o);
  float inv = rsqrtf(vs / (float)width + 1e-5f);
  for (int c = 0; c < chunks; ++c) {
    int off = c * 256 + lane * 4;
    float4 g4 = *(const float4*)&gam[off];
    float4 b4 = *(const float4*)&bet[off];
    float y[4] = {(v[c].x - mean) * inv * g4.x + b4.x,
                  (v[c].y - mean) * inv * g4.y + b4.y,
                  (v[c].z - mean) * inv * g4.z + b4.z,
                  (v[c].w - mean) * inv * g4.w + b4.w};
    if (do_gelu) {
#pragma unroll
      for (int i = 0; i < 4; ++i) y[i] = gelu_f(y[i]);
    }
    size_t idx = (size_t)wid * width + off;
    float4 o4 = {y[0], y[1], y[2], y[3]};
    *(float4*)&out[idx] = o4;
    if (outb) {
      ushort4 ob = {bfr(y[0]), bfr(y[1]), bfr(y[2]), bfr(y[3])};
      *(ushort4*)&outb[idx] = ob;
    }
  }
}

// ---------- CSR build (two-level scan; block prefix folded into scan3) ----------
__global__ __launch_bounds__(256) void edge_count(const int* __restrict__ ei,
                                                  int* __restrict__ counts) {
  int e = blockIdx.x * 256 + threadIdx.x;
  if (e < N_EDGES) atomicAdd(&counts[ei[N_EDGES + e]], 1);
}

__global__ __launch_bounds__(1024) void scan1(const int* __restrict__ counts,
                                              int* __restrict__ indptr,
                                              int* __restrict__ bsums, int n) {
  __shared__ int sm[1024];
  int tid = threadIdx.x;
  int i = blockIdx.x * 1024 + tid;
  int v = (i < n) ? counts[i] : 0;
  sm[tid] = v;
  __syncthreads();
  for (int off = 1; off < 1024; off <<= 1) {
    int t = (tid >= off) ? sm[tid - off] : 0;
    __syncthreads();
    sm[tid] += t;
    __syncthreads();
  }
  if (i < n) indptr[i] = sm[tid] - v;  // block-local exclusive
  if (tid == 1023) bsums[blockIdx.x] = sm[1023];
}

__global__ __launch_bounds__(256) void scan3(const int* __restrict__ bsums,
                                             int* __restrict__ indptr,
                                             int* __restrict__ cursor, int n) {
  __shared__ int pre;
  int i = blockIdx.x * 256 + threadIdx.x;
  if (threadIdx.x == 0) {
    int nb = blockIdx.x >> 2;  // i>>10 constant within a 256-block
    int a = 0;
    for (int j = 0; j < nb; ++j) a += bsums[j];
    pre = a;
  }
  __syncthreads();
  if (i < n) {
    int v = indptr[i] + pre;
    indptr[i] = v;
    cursor[i] = v;
  }
  if (i == 0) indptr[n] = N_EDGES;
}

__global__ __launch_bounds__(256) void edge_scatter(const int* __restrict__ ei,
                                                    int* __restrict__ cursor,
                                                    int* __restrict__ esrc) {
  int e = blockIdx.x * 256 + threadIdx.x;
  if (e < N_EDGES) {
    int d = ei[N_EDGES + e];
    int p = atomicAdd(&cursor[d], 1);
    esrc[p] = ei[e];
  }
}

// ---------- GATv2 agg + bias + LN + GELU + residual (fused, branchless) ----------
// xlr[N][512] bf16 rows = [xl|xr]; writes h (fp32) and hb (bf16).
// Softmax anchored on self-loop score (shift-invariant; scores O(1), clamp +60).
#define GAT_EDGE(f)                                                        \
  {                                                                        \
    float ex = f.x + xri.x; ex = fmaxf(ex, 0.2f * ex);                     \
    float ey = f.y + xri.y; ey = fmaxf(ey, 0.2f * ey);                     \
    float ez = f.z + xri.z; ez = fmaxf(ez, 0.2f * ez);                     \
    float ew = f.w + xri.w; ew = fmaxf(ew, 0.2f * ew);                     \
    float p = ex * a4.x + ey * a4.y + ez * a4.z + ew * a4.w;               \
    p += __shfl_xor(p, 1); p += __shfl_xor(p, 2); p += __shfl_xor(p, 4);   \
    float wgt = __expf(fminf(p - m0, 60.f));                               \
    ax = fmaf(wgt, f.x, ax); ay = fmaf(wgt, f.y, ay);                      \
    az = fmaf(wgt, f.z, az); aw = fmaf(wgt, f.w, aw);                      \
    lsum += wgt;                                                           \
  }

__global__ __launch_bounds__(256) void gat_agg(
    const unsigned short* __restrict__ xlr, const float* __restrict__ att,
    const int* __restrict__ indptr, const int* __restrict__ esrc,
    const float* __restrict__ pre_bias, const float* __restrict__ gam,
    const float* __restrict__ bet, float* __restrict__ h,
    unsigned short* __restrict__ hb) {
  int wid = blockIdx.x * 4 + (threadIdx.x >> 6);
  int lane = threadIdx.x & 63;
  if (wid >= N_NODES) return;
  float4 xri = ld4bf(&xlr[(size_t)wid * 512 + 256 + lane * 4]);
  float4 a4 = *(const float4*)&att[lane * 4];
  int beg = indptr[wid], end = indptr[wid + 1];

  float m0, lsum, ax, ay, az, aw;
  {  // self loop = softmax anchor
    float4 f = ld4bf(&xlr[(size_t)wid * 512 + lane * 4]);
    float ex = f.x + xri.x; ex = fmaxf(ex, 0.2f * ex);
    float ey = f.y + xri.y; ey = fmaxf(ey, 0.2f * ey);
    float ez = f.z + xri.z; ez = fmaxf(ez, 0.2f * ez);
    float ew = f.w + xri.w; ew = fmaxf(ew, 0.2f * ew);
    float p = ex * a4.x + ey * a4.y + ez * a4.z + ew * a4.w;
    p += __shfl_xor(p, 1); p += __shfl_xor(p, 2); p += __shfl_xor(p, 4);
    m0 = p; lsum = 1.f;
    ax = f.x; ay = f.y; az = f.z; aw = f.w;
  }
  const unsigned short* xbase = xlr + lane * 4;
  int e = beg;
  for (; e + 3 < end; e += 4) {  // 4 gathers in flight
    int j0 = esrc[e], j1 = esrc[e + 1], j2 = esrc[e + 2], j3 = esrc[e + 3];
    float4 f0 = ld4bf(xbase + (size_t)j0 * 512);
    float4 f1 = ld4bf(xbase + (size_t)j1 * 512);
    float4 f2 = ld4bf(xbase + (size_t)j2 * 512);
    float4 f3 = ld4bf(xbase + (size_t)j3 * 512);
    GAT_EDGE(f0); GAT_EDGE(f1); GAT_EDGE(f2); GAT_EDGE(f3);
  }
  for (; e < end; ++e) {
    int j = esrc[e];
    float4 f = ld4bf(xbase + (size_t)j * 512);
    GAT_EDGE(f);
  }
  float inv = 1.f / (lsum + 1e-16f);
  float4 pb = *(const float4*)&pre_bias[lane * 4];
  float y0 = ax * inv + pb.x, y1 = ay * inv + pb.y;
  float y2 = az * inv + pb.z, y3 = aw * inv + pb.w;
  // LN over 256
  float s = y0 + y1 + y2 + y3;
  for (int o = 1; o < 64; o <<= 1) s += __shfl_xor(s, o);
  float mean = s * (1.f / 256.f);
  float d0 = y0 - mean, d1 = y1 - mean, d2 = y2 - mean, d3 = y3 - mean;
  float vs = d0 * d0 + d1 * d1 + d2 * d2 + d3 * d3;
  for (int o = 1; o < 64; o <<= 1) vs += __shfl_xor(vs, o);
  float inv2 = rsqrtf(vs * (1.f / 256.f) + 1e-5f);
  float4 g4 = *(const float4*)&gam[lane * 4];
  float4 b4 = *(const float4*)&bet[lane * 4];
  y0 = gelu_f(d0 * inv2 * g4.x + b4.x);
  y1 = gelu_f(d1 * inv2 * g4.y + b4.y);
  y2 = gelu_f(d2 * inv2 * g4.z + b4.z);
  y3 = gelu_f(d3 * inv2 * g4.w + b4.w);
  size_t idx = (size_t)wid * HID + lane * 4;
  float4 r4 = *(const float4*)&h[idx];
  y0 += r4.x; y1 += r4.y; y2 += r4.z; y3 += r4.w;
  float4 o4 = {y0, y1, y2, y3};
  *(float4*)&h[idx] = o4;
  ushort4 ob = {bfr(y0), bfr(y1), bfr(y2), bfr(y3)};
  *(ushort4*)&hb[idx] = ob;
}

// ---------- TransformerConv agg + skip + LN + residual (fused, branchless) ----------
// qkv[N][1024] bf16 rows = [q | kv-interleaved | skip]; per edge ONE dwordx4
// gives lane's k[4] (u_.x,u_.y) and v[4] (u_.z,u_.w). scale pre-folded into qi.
#define TR_EDGE(u_)                                                         \
  {                                                                         \
    float p = qi.x * b2f_lo(u_.x);                                          \
    p = fmaf(qi.y, b2f_hi(u_.x), p);                                        \
    p = fmaf(qi.z, b2f_lo(u_.y), p);                                        \
    p = fmaf(qi.w, b2f_hi(u_.y), p);                                        \
    p += __shfl_xor(p, 1); p += __shfl_xor(p, 2); p += __shfl_xor(p, 4);    \
    float wgt = __expf(fminf(p, 60.f));                                     \
    ax = fmaf(wgt, b2f_lo(u_.z), ax); ay = fmaf(wgt, b2f_hi(u_.z), ay);     \
    az = fmaf(wgt, b2f_lo(u_.w), az); aw = fmaf(wgt, b2f_hi(u_.w), aw);     \
    lsum += wgt;                                                            \
  }

__global__ __launch_bounds__(256) void tr_agg(
    const unsigned short* __restrict__ qkv, const int* __restrict__ indptr,
    const int* __restrict__ esrc,
    const float* __restrict__ gam, const float* __restrict__ bet,
    float* __restrict__ h) {
  int wid = blockIdx.x * 4 + (threadIdx.x >> 6);
  int lane = threadIdx.x & 63;
  if (wid >= N_NODES) return;
  const float scale = 0.17677669529663687f;
  float4 qi = ld4bf(&qkv[(size_t)wid * 1024 + lane * 4]);
  qi.x *= scale; qi.y *= scale; qi.z *= scale; qi.w *= scale;
  const unsigned short* kvbase = qkv + 256 + lane * 8;
  int beg = indptr[wid], end = indptr[wid + 1];
  float lsum = 0.f;
  float ax = 0.f, ay = 0.f, az = 0.f, aw = 0.f;
  int e = beg;
  for (; e + 3 < end; e += 4) {  // 4 dwordx4 gathers in flight
    int j0 = esrc[e], j1 = esrc[e + 1], j2 = esrc[e + 2], j3 = esrc[e + 3];
    uint4 u0 = *(const uint4*)(kvbase + (size_t)j0 * 1024);
    uint4 u1 = *(const uint4*)(kvbase + (size_t)j1 * 1024);
    uint4 u2 = *(const uint4*)(kvbase + (size_t)j2 * 1024);
    uint4 u3 = *(const uint4*)(kvbase + (size_t)j3 * 1024);
    TR_EDGE(u0); TR_EDGE(u1); TR_EDGE(u2); TR_EDGE(u3);
  }
  for (; e < end; ++e) {
    uint4 u0 = *(const uint4*)(kvbase + (size_t)esrc[e] * 1024);
    TR_EDGE(u0);
  }
  float inv = 1.f / (lsum + 1e-16f);
  size_t idx = (size_t)wid * HID + lane * 4;
  float4 sk = ld4bf(&qkv[(size_t)wid * 1024 + 768 + lane * 4]);
  float y0 = ax * inv + sk.x, y1 = ay * inv + sk.y;
  float y2 = az * inv + sk.z, y3 = aw * inv + sk.w;
  // LN over 256 (no gelu)
  float s = y0 + y1 + y2 + y3;
  for (int o = 1; o < 64; o <<= 1) s += __shfl_xor(s, o);
  float mean = s * (1.f / 256.f);
  float d0 = y0 - mean, d1 = y1 - mean, d2 = y2 - mean, d3 = y3 - mean;
  float vs = d0 * d0 + d1 * d1 + d2 * d2 + d3 * d3;
  for (int o = 1; o < 64; o <<= 1) vs += __shfl_xor(vs, o);
  float inv2 = rsqrtf(vs * (1.f / 256.f) + 1e-5f);
  float4 g4 = *(const float4*)&gam[lane * 4];
  float4 b4 = *(const float4*)&bet[lane * 4];
  float4 r4 = *(const float4*)&h[idx];
  float4 o4;
  o4.x = r4.x + d0 * inv2 * g4.x + b4.x;
  o4.y = r4.y + d1 * inv2 * g4.y + b4.y;
  o4.z = r4.z + d2 * inv2 * g4.z + b4.z;
  o4.w = r4.w + d3 * inv2 * g4.w + b4.w;
  *(float4*)&h[idx] = o4;
}

// ---------- pooling over sorted batch ----------
__global__ __launch_bounds__(256) void graph_bounds(const int* __restrict__ batch,
                                                    int* __restrict__ gptr) {
  int i = blockIdx.x * 256 + threadIdx.x;
  if (i >= N_NODES) return;
  int b0 = batch[i];
  if (i == 0)
    for (int g = 0; g <= b0; ++g) gptr[g] = 0;
  int b1 = (i + 1 < N_NODES) ? batch[i + 1] : N_GRAPH;
  for (int g = b0 + 1; g <= b1; ++g) gptr[g] = i + 1;
}

__global__ __launch_bounds__(256) void pool_seg(
    const float* __restrict__ h, const int* __restrict__ gptr,
    unsigned short* __restrict__ geb) {
  int g = blockIdx.x, c = threadIdx.x;
  int s = gptr[g], e = gptr[g + 1];
  float sum = 0.f, mx = -INFINITY;
  for (int r = s; r < e; ++r) {
    float vv = h[(size_t)r * HID + c];
    sum += vv;
    mx = fmaxf(mx, vv);
  }
  int cnt = e - s;
  geb[(size_t)g * 512 + c] = bfr(sum / (float)max(cnt, 1));
  geb[(size_t)g * 512 + 256 + c] = bfr(cnt ? mx : 0.f);
}

// ---------- host ----------
static inline void mfma_launch(const unsigned short* A, const unsigned short* Bt,
                               const float* bias, void* C, int M, int Nn, int K,
                               int flags, hipStream_t s) {
  dim3 grid(Nn / 128, (M + 127) / 128);
  gemm_mfma<<<grid, 256, 0, s>>>(A, Bt, bias, C, M, Nn, K, flags);
}

extern "C" void kernel_launch(void* const* d_in, const int* in_sizes, int n_in,
                              void* d_out, int out_size, void* d_ws, size_t ws_size,
                              hipStream_t stream) {
  const float* x       = (const float*)d_in[0];
  const int*   ei      = (const int*)d_in[1];
  const int*   batch   = (const int*)d_in[2];
  const float* in_W    = (const float*)d_in[3];
  const float* in_b    = (const float*)d_in[4];
  const float* in_ln_g = (const float*)d_in[5];
  const float* in_ln_b = (const float*)d_in[6];
  const float* gat_Wl  = (const float*)d_in[7];
  const float* gat_bl  = (const float*)d_in[8];
  const float* gat_Wr  = (const float*)d_in[9];
  const float* gat_br  = (const float*)d_in[10];
  const float* gat_att = (const float*)d_in[11];
  const float* gat_bias= (const float*)d_in[12];
  const float* gat_ln_g= (const float*)d_in[13];
  const float* gat_ln_b= (const float*)d_in[14];
  const float* tr_Wq   = (const float*)d_in[15];
  const float* tr_bq   = (const float*)d_in[16];
  const float* tr_Wk   = (const float*)d_in[17];
  const float* tr_bk   = (const float*)d_in[18];
  const float* tr_Wv   = (const float*)d_in[19];
  const float* tr_bv   = (const float*)d_in[20];
  const float* tr_Wsk  = (const float*)d_in[21];
  const float* tr_bsk  = (const float*)d_in[22];
  const float* tr_ln_g = (const float*)d_in[23];
  const float* tr_ln_b = (const float*)d_in[24];
  const float* out_W   = (const float*)d_in[25];
  const float* out_b   = (const float*)d_in[26];
  const float* out_ln_g= (const float*)d_in[27];
  const float* out_ln_b= (const float*)d_in[28];

  // ---- workspace (256B-aligned) ----
  char* w = (char*)d_ws;
  auto take = [&](size_t bytes) -> char* {
    char* p = w;
    w += (bytes + 255) & ~(size_t)255;
    return p;
  };
  const size_t NB = (size_t)N_NODES * HID * sizeof(float);
  float* h    = (float*)take(NB);                                    // 51.2 MB
  unsigned short* hb  = (unsigned short*)take((size_t)N_NODES * HID * 2);   // 25.6 MB
  unsigned short* xq  = (unsigned short*)take((size_t)N_NODES * 1024 * 2);  // 102.4 MB
  unsigned short* wbuf= (unsigned short*)take((size_t)(14 * 65536 + 262144) * 2);
  float* bcat = (float*)take(3584 * sizeof(float));
  int* indptr = (int*)take((N_NODES + 1) * sizeof(int));
  int* cursor = (int*)take(N_NODES * sizeof(int));
  int* counts = (int*)take(N_NODES * sizeof(int));
  int* esrc   = (int*)take(N_EDGES * sizeof(int));
  int* bsums  = (int*)take(64 * sizeof(int));
  // pool/output scratch overlays xq (free after tr_agg)
  char* w2 = (char*)xq;
  auto take2 = [&](size_t bytes) -> char* {
    char* p = w2;
    w2 += (bytes + 255) & ~(size_t)255;
    return p;
  };
  int* gptr = (int*)take2((N_GRAPH + 1) * sizeof(int));
  unsigned short* geb = (unsigned short*)take2((size_t)N_GRAPH * 512 * 2);
  float* tbuf = (float*)take2((size_t)N_GRAPH * 512 * sizeof(float));

  const int EB = (N_EDGES + 255) / 256;
  const int WB = (N_NODES + 3) / 4;
  const int NSB = (N_NODES + 1023) / 1024;

  // --- merged weight/bias prep (1 dispatch) ---
  {
    dim3 g(16, 16, 16);
    prep_all<<<g, 256, 0, stream>>>(gat_Wl, gat_Wr, tr_Wq, tr_Wk, tr_Wv, tr_Wsk,
                                    wbuf, out_W, wbuf + (size_t)14 * 65536,
                                    gat_bl, gat_br, tr_bq, tr_bk, tr_bv, tr_bsk,
                                    bcat);
  }

  // --- CSR (dst-sorted), two-level scan (scan2 folded into scan3) ---
  hipMemsetAsync(counts, 0, N_NODES * sizeof(int), stream);
  edge_count<<<EB, 256, 0, stream>>>(ei, counts);
  scan1<<<NSB, 1024, 0, stream>>>(counts, indptr, bsums, N_NODES);
  scan3<<<(N_NODES + 255) / 256, 256, 0, stream>>>(bsums, indptr, cursor, N_NODES);
  edge_scatter<<<EB, 256, 0, stream>>>(ei, cursor, esrc);

  // --- fused input embed: h = gelu(LN(x @ in_W + in_b)), hb = bf16(h) ---
  embed_fused<<<N_NODES / 16, 256, 0, stream>>>(x, in_W, in_b, in_ln_g, in_ln_b,
                                                h, hb);

  // --- 5 GATv2 layers: fused Wl|Wr GEMM -> xq[N][512] bf16; fused agg+LN ---
  for (int l = 0; l < NLAYER; ++l) {
    mfma_launch(hb, wbuf + (size_t)(2 * l) * 65536, bcat + l * 512, xq,
                N_NODES, 512, HID, 2, stream);
    gat_agg<<<WB, 256, 0, stream>>>(xq, gat_att + l * HID, indptr, esrc,
                                    gat_bias + l * HID, gat_ln_g + l * HID,
                                    gat_ln_b + l * HID, h, hb);
  }

  // --- TransformerConv: merged q|kv|skip GEMM (Nn=1024), fused agg+LN ---
  mfma_launch(hb, wbuf + (size_t)10 * 65536, bcat + 2560, xq,
              N_NODES, 1024, HID, 2, stream);
  tr_agg<<<WB, 256, 0, stream>>>(xq, indptr, esrc, tr_ln_g, tr_ln_b, h);

  // --- pooling (sorted batch; scratch overlays xq, now free) -> geb bf16 ---
  graph_bounds<<<(N_NODES + 255) / 256, 256, 0, stream>>>(batch, gptr);
  pool_seg<<<N_GRAPH, 256, 0, stream>>>(h, gptr, geb);

  // --- output proj (MFMA): tbuf = geb @ out_W + out_b ; then LN+GELU ---
  mfma_launch(geb, wbuf + (size_t)14 * 65536, out_b, tbuf,
              N_GRAPH, 512, 512, 0, stream);
  ln_act<<<(N_GRAPH + 3) / 4, 256, 0, stream>>>(tbuf, out_ln_g, out_ln_b,
                                                (float*)d_out, nullptr,
                                                N_GRAPH, 512, 1);
}